// Round 10
// baseline (1123.689 us; speedup 1.0000x reference)
//
#include <hip/hip_runtime.h>
#include <hip/hip_bf16.h>
#include <cmath>

#define DIM 512
#define HID 256

typedef __attribute__((ext_vector_type(8))) short short8;
typedef __attribute__((ext_vector_type(4))) float f32x4;

__device__ __forceinline__ unsigned short f2bf(float f) {
  union { float f; unsigned u; } v; v.f = f;
  unsigned u = v.u;
  return (unsigned short)((u + 0x7FFFu + ((u >> 16) & 1u)) >> 16);
}

// Pre-swizzle W1 (fp32 [512,256] row-major) into bf16 MFMA fragment order:
// w1s short8-index kg*256 + c  (kg = k>>3) holds the 16B fragment {k-group
// kg, hidden col c}.
__global__ void w1_swz_kernel(const float* __restrict__ W1,
                              unsigned short* __restrict__ w1s) {
  int tid = blockIdx.x * blockDim.x + threadIdx.x;
  if (tid >= DIM * HID) return;
  int k = tid / HID;
  int c = tid - k * HID;
  w1s[(((k >> 3) * HID) + c) * 8 + (k & 7)] = f2bf(W1[tid]);
}

__device__ __forceinline__ short8 cvt8(const f32x4 p0, const f32x4 p1) {
  short8 r;
  r[0] = (short)f2bf(p0[0]); r[1] = (short)f2bf(p0[1]);
  r[2] = (short)f2bf(p0[2]); r[3] = (short)f2bf(p0[3]);
  r[4] = (short)f2bf(p1[0]); r[5] = (short)f2bf(p1[1]);
  r[6] = (short)f2bf(p1[2]); r[7] = (short)f2bf(p1[3]);
  return r;
}

// K1: persistent-B logits. Block (h = bid&1, cid = bid>>1): holds B-half h
// (all 512 k x 128 cols, 128 KB bf16) in LDS for its whole life; streams
// rows [cid*rpc, cid*rpc+rpc) of BOTH sources (wave w: src = w&1, tile
// stride 4), writing partial logits pl[(h*2+s)*n + row]. ReLU is complete
// within a half (full K resident), so halves just sum.
__global__ __launch_bounds__(512, 2) void fa_logits_kernel(
    const float* __restrict__ z1, const float* __restrict__ z2,
    const unsigned short* __restrict__ w1s, const float* __restrict__ bias1,
    const float* __restrict__ W2, float* __restrict__ pl, int n, int rpc) {
  __shared__ short8 Bh[8192];  // 128 KB B-half, fragment order

  const int t = threadIdx.x, w = t >> 6, l = t & 63;
  const int l15 = l & 15, l16 = l >> 4;
  const int h = blockIdx.x & 1, cid = blockIdx.x >> 1;
  const int s = w & 1;
  const int row_lo = cid * rpc;
  const int row_hi = min(n, row_lo + rpc);
  if (row_lo >= n) return;  // block-uniform exit

  // Stage B-half once: 128 pieces of 1KB. Piece p = kg*2+ph covers cols
  // h*128+ph*64+[0,64) of k-group kg. Global src per-lane, LDS dest linear.
  for (int p = w; p < 128; p += 8) {
    const char* gsrc =
        (const char*)w1s + (size_t)(((p >> 1) << 8) + (h << 7) +
                                    ((p & 1) << 6) + l) * 16;
    __builtin_amdgcn_global_load_lds(
        (const __attribute__((address_space(1))) void*)gsrc,
        (__attribute__((address_space(3))) void*)((char*)&Bh[0] + p * 1024),
        16, 0, 0);
  }

  const float* zz = s ? z2 : z1;
  const f32x4 zf4 = (f32x4){0.f, 0.f, 0.f, 0.f};

#define LOAD8(T0, dst, COFF)                                              \
  {                                                                       \
    const int mr = (T0) + l15;                                            \
    const bool ok = mr < row_hi;                                          \
    const float* ap = zz + (size_t)mr * DIM + (l16 << 3) + (COFF);        \
    _Pragma("unroll") for (int j = 0; j < 8; ++j) {                       \
      dst[j][0] = ok ? *(const f32x4*)(ap + (j << 5)) : zf4;              \
      dst[j][1] = ok ? *(const f32x4*)(ap + (j << 5) + 4) : zf4;          \
    }                                                                     \
  }

  // Fragment (chunk c, colfrag f): LDS short8-idx
  //   (kg*2 + (f>>2))*64 + (f&3)*16 + l15,  kg = c*4 + l16.
#define KLOOP(afarr, CBASE)                                               \
  _Pragma("unroll") for (int c = 0; c < 8; ++c) {                         \
    const int kg2 = (((CBASE) + c) * 4 + l16) * 2;                        \
    _Pragma("unroll") for (int f = 0; f < 8; ++f) {                       \
      const short8 bf = Bh[(kg2 + (f >> 2)) * 64 + ((f & 3) << 4) + l15]; \
      acc[f] =                                                            \
          __builtin_amdgcn_mfma_f32_16x16x32_bf16(afarr[c], bf, acc[f],   \
                                                  0, 0, 0);               \
    }                                                                     \
  }

  // Prime first tile's low half (issued before the staging sync).
  const int tstart = row_lo + (w >> 1) * 16;
  f32x4 plo[8][2];
  if (tstart < row_hi) LOAD8(tstart, plo, 0);

  __syncthreads();  // B-half resident; the only barrier in the kernel

  for (int t0 = tstart; t0 < row_hi; t0 += 64) {
    short8 aflo[8], afhi[8];
#pragma unroll
    for (int j = 0; j < 8; ++j) aflo[j] = cvt8(plo[j][0], plo[j][1]);
    f32x4 phi[8][2];
    LOAD8(t0, phi, 256);  // high K-half, in flight under KLOOP lo

    f32x4 acc[8];
#pragma unroll
    for (int f = 0; f < 8; ++f) acc[f] = zf4;

    KLOOP(aflo, 0);
#pragma unroll
    for (int j = 0; j < 8; ++j) afhi[j] = cvt8(phi[j][0], phi[j][1]);
    if (t0 + 64 < row_hi) LOAD8(t0 + 64, plo, 0);  // next tile, in flight
    KLOOP(afhi, 8);

    // Partial logit over this half: col = h*128 + f*16 + l15,
    // row-in-tile = l16*4 + r.
    float part[4] = {0.f, 0.f, 0.f, 0.f};
#pragma unroll
    for (int f = 0; f < 8; ++f) {
      const int cc = (h << 7) + (f << 4) + l15;
      const float w2v = W2[cc];
      const float b1v = bias1[cc];
#pragma unroll
      for (int r = 0; r < 4; ++r) {
        const float hh = acc[f][r] + b1v;
        part[r] += (hh > 0.f) ? hh * w2v : 0.f;
      }
    }
#pragma unroll
    for (int r = 0; r < 4; ++r) {
#pragma unroll
      for (int m = 1; m < 16; m <<= 1) part[r] += __shfl_xor(part[r], m, 16);
    }
    if (l15 == 0) {
#pragma unroll
      for (int r = 0; r < 4; ++r) {
        const int rr = t0 + (l16 << 2) + r;
        if (rr < row_hi) pl[(size_t)((h << 1) | s) * n + rr] = part[r];
      }
    }
  }
#undef LOAD8
#undef KLOOP
}

// K2: pure streaming combine. out = sx*z1 + (1-sx)*z2,
// sx = sigmoid(x - y), x = pl[0]+pl[2], y = pl[1]+pl[3] (b2 cancels).
__global__ __launch_bounds__(256) void fa_combine_kernel(
    const float* __restrict__ z1, const float* __restrict__ z2,
    const float* __restrict__ pl, float* __restrict__ out, int n) {
  const int total = n * (DIM / 4);
  const int stride = gridDim.x * 256;
  const f32x4* a4 = (const f32x4*)z1;
  const f32x4* b4 = (const f32x4*)z2;
  f32x4* o4 = (f32x4*)out;
#pragma unroll 4
  for (int i = blockIdx.x * 256 + threadIdx.x; i < total; i += stride) {
    const int row = i >> 7;
    const float x = pl[row] + pl[2 * n + row];
    const float y = pl[n + row] + pl[3 * n + row];
    const float sx = 1.f / (1.f + __expf(y - x));
    const float sy = 1.f - sx;
    const f32x4 a = a4[i];
    const f32x4 b = b4[i];
    f32x4 o;
    o[0] = sx * a[0] + sy * b[0];
    o[1] = sx * a[1] + sy * b[1];
    o[2] = sx * a[2] + sy * b[2];
    o[3] = sx * a[3] + sy * b[3];
    o4[i] = o;
  }
}

extern "C" void kernel_launch(void* const* d_in, const int* in_sizes, int n_in,
                              void* d_out, int out_size, void* d_ws,
                              size_t ws_size, hipStream_t stream) {
  const float* z1 = (const float*)d_in[0];
  const float* z2 = (const float*)d_in[1];
  const float* W1 = (const float*)d_in[2];
  const float* b1 = (const float*)d_in[3];
  const float* W2 = (const float*)d_in[4];
  const float* b2 = (const float*)d_in[5];
  float* out = (float*)d_out;
  const int n = in_sizes[0] / DIM;

  unsigned short* w1s = (unsigned short*)d_ws;          // 256 KB
  float* pl = (float*)((char*)d_ws + 262144);           // 4*n floats

  hipLaunchKernelGGL(w1_swz_kernel, dim3((DIM * HID + 255) / 256), dim3(256),
                     0, stream, W1, w1s);

  const int rpc = (n + 255) / 256;  // rows per chunk (256 chunks x 2 halves)
  hipLaunchKernelGGL(fa_logits_kernel, dim3(512), dim3(512), 0, stream, z1,
                     z2, w1s, b1, W2, pl, n, rpc);

  hipLaunchKernelGGL(fa_combine_kernel, dim3(2048), dim3(256), 0, stream, z1,
                     z2, pl, out, n);
}

// Round 11
// 206.678 us; speedup vs baseline: 5.4369x; 5.4369x over previous
//
#include <hip/hip_runtime.h>
#include <hip/hip_bf16.h>
#include <cmath>

#define DIM 512
#define HID 256
#define ROWS_PB 16       // rows per block (100000 = 6250 * 16, no tail)
#define NCHUNK 16        // K chunks of 32
#define CB 16384         // B chunk bytes: 32k * 256c * 2B

typedef __attribute__((ext_vector_type(8))) short short8;
typedef __attribute__((ext_vector_type(4))) float f32x4;
typedef __attribute__((ext_vector_type(4))) unsigned int u32x4;

__device__ __forceinline__ unsigned short f2bf(float f) {
  union { float f; unsigned u; } v; v.f = f;
  unsigned u = v.u;
  return (unsigned short)((u + 0x7FFFu + ((u >> 16) & 1u)) >> 16);
}
__device__ __forceinline__ float bf2f(short h) {
  union { unsigned u; float f; } v;
  v.u = ((unsigned)(unsigned short)h) << 16;
  return v.f;
}

// Pre-swizzle W1 (fp32 [512,256] row-major) into bf16 MFMA fragment order:
// w1s[((k>>3)*HID + c)*8 + (k&7)]. K-chunk c (32 k's) is the contiguous
// 16 KB at byte offset c*16384 — a linear copy.
__global__ void w1_swz_kernel(const float* __restrict__ W1,
                              unsigned short* __restrict__ w1s) {
  int tid = blockIdx.x * blockDim.x + threadIdx.x;
  if (tid >= DIM * HID) return;
  int k = tid / HID;
  int c = tid - k * HID;
  w1s[(((k >> 3) * HID) + c) * 8 + (k & 7)] = f2bf(W1[tid]);
}

__device__ __forceinline__ short8 cvt8(const f32x4 p0, const f32x4 p1) {
  short8 r;
  r[0] = (short)f2bf(p0[0]); r[1] = (short)f2bf(p0[1]);
  r[2] = (short)f2bf(p0[2]); r[3] = (short)f2bf(p0[3]);
  r[4] = (short)f2bf(p1[0]); r[5] = (short)f2bf(p1[1]);
  r[6] = (short)f2bf(p1[2]); r[7] = (short)f2bf(p1[3]);
  return r;
}

__device__ __forceinline__ void wcombine(float wa, const short8 a, float wb,
                                         const short8 b, f32x4& o0, f32x4& o1) {
#pragma unroll
  for (int i = 0; i < 4; ++i) {
    o0[i] = wa * bf2f(a[i]) + wb * bf2f(b[i]);
    o1[i] = wa * bf2f(a[i + 4]) + wb * bf2f(b[i + 4]);
  }
}

// 4 waves / 16 rows. Wave w: src s=w&1 (z1/z2), hid-half h=w>>1.
// Phase 1: deep HBM burst -> Az bf16 fragments in LDS (z read ONCE).
// Phase 2: K-loop, double-buffered B with T14 reg-staging: global_load
//          B[c+1] -> 16 VGPRs issued BEFORE the MFMAs (sched_barrier-pinned),
//          ds_write AFTER them. The __syncthreads vmcnt drain then finds the
//          loads already complete — no exposed latency, no raw-barrier races.
// Phase 3: HID-split logits combined via LDS; out computed from Az only.
__global__ __launch_bounds__(256, 2) void fa_main_kernel(
    const float* __restrict__ z1, const float* __restrict__ z2,
    const unsigned short* __restrict__ w1s,
    const float* __restrict__ bias1, const float* __restrict__ W2,
    const float* __restrict__ bias2, float* __restrict__ out, int n) {
  __shared__ short8 Az[2 * NCHUNK * 64];  // 32 KB: [src][chunk][lane]
  __shared__ char Bbuf[2][CB];            // 32 KB double buffer
  __shared__ float xs2[2][2][ROWS_PB];    // partial logits [src][half][row]

  const int t = threadIdx.x;
  const int w = t >> 6;
  const int l = t & 63;
  const int l15 = l & 15, l16 = l >> 4;
  const int s = w & 1;   // source this wave stages/scores
  const int h = w >> 1;  // hid-half this wave computes
  const int row0 = blockIdx.x * ROWS_PB;
  const int myrow = row0 + l15;
  const bool rok = myrow < n;
  const float* zz = s ? z2 : z1;
  const float* ap = zz + (size_t)myrow * DIM + (l16 << 3);
  const f32x4 zf4 = (f32x4){0.f, 0.f, 0.f, 0.f};

  // T14 reg-staging: 64 B/thread per chunk (4 x 16 B pieces).
  u32x4 breg0, breg1, breg2, breg3;
#define BLOAD(c)                                            \
  {                                                         \
    const u32x4* g = (const u32x4*)w1s + (c) * 1024 + t;    \
    breg0 = g[0];                                           \
    breg1 = g[256];                                         \
    breg2 = g[512];                                         \
    breg3 = g[768];                                         \
  }
#define BWRITE(c)                                           \
  {                                                         \
    u32x4* d = (u32x4*)&Bbuf[(c) & 1][0] + t;               \
    d[0] = breg0;                                           \
    d[256] = breg1;                                         \
    d[512] = breg2;                                         \
    d[768] = breg3;                                         \
  }

  // Phase 1: issue B[0] (L2) first, then the A burst (HBM, 16 indep 16B
  // loads/lane); write B[0] (waits only breg), then Az (waits A), sync.
  BLOAD(0);
  __builtin_amdgcn_sched_barrier(0);
  {
    f32x4 pp[8][2];
#pragma unroll
    for (int j = 0; j < 8; ++j) {
      const float* p = ap + ((h * 8 + j) << 5);
      pp[j][0] = rok ? *(const f32x4*)(p) : zf4;
      pp[j][1] = rok ? *(const f32x4*)(p + 4) : zf4;
    }
    BWRITE(0);
#pragma unroll
    for (int j = 0; j < 8; ++j)
      Az[(s * NCHUNK + h * 8 + j) * 64 + l] = cvt8(pp[j][0], pp[j][1]);
  }
  __syncthreads();  // Az + B[0] resident

  // Hoist A-fragments (Az stays immutable for the epilogue).
  short8 af[NCHUNK];
#pragma unroll
  for (int c = 0; c < NCHUNK; ++c) af[c] = Az[(s * NCHUNK + c) * 64 + l];

  f32x4 acc[8];
#pragma unroll
  for (int f = 0; f < 8; ++f) acc[f] = zf4;

  // Phase 2: K-loop. BLOAD early (pinned), MFMAs cover the L2 latency,
  // BWRITE late, one __syncthreads per chunk. BWRITE(c+1) targets the
  // buffer last read in chunk c-1 — protected by that chunk's barrier.
#pragma unroll
  for (int c = 0; c < NCHUNK; ++c) {
    if (c + 1 < NCHUNK) BLOAD(c + 1);
    __builtin_amdgcn_sched_barrier(0);  // pin the early issue point
    const short8* bp =
        (const short8*)&Bbuf[c & 1][0] + (l16 << 8) + (h << 7) + l15;
#pragma unroll
    for (int f = 0; f < 8; ++f) {
      const short8 bf = bp[f << 4];
      acc[f] =
          __builtin_amdgcn_mfma_f32_16x16x32_bf16(af[c], bf, acc[f], 0, 0, 0);
    }
    if (c + 1 < NCHUNK) BWRITE(c + 1);
    __syncthreads();
  }

  // Phase 3a: partial logit over this wave's hid-half.
  // C/D: hidden col = h*128 + f*16 + l15, row-in-tile = l16*4 + r.
  float part[4] = {0.f, 0.f, 0.f, 0.f};
#pragma unroll
  for (int f = 0; f < 8; ++f) {
    const int cc = (h << 7) + (f << 4) + l15;
    const float w2v = W2[cc];
    const float b1v = bias1[cc];
#pragma unroll
    for (int r = 0; r < 4; ++r) {
      const float hh = acc[f][r] + b1v;
      part[r] += (hh > 0.f) ? hh * w2v : 0.f;
    }
  }
#pragma unroll
  for (int r = 0; r < 4; ++r) {
#pragma unroll
    for (int m = 1; m < 16; m <<= 1) part[r] += __shfl_xor(part[r], m, 16);
  }
  if (l15 == 0) {
#pragma unroll
    for (int r = 0; r < 4; ++r) xs2[s][h][(l16 << 2) + r] = part[r];
  }
  __syncthreads();

  // Phase 3b: scores + output, entirely from Az (no HBM reads).
  const float x = xs2[0][0][l15] + xs2[0][1][l15];
  const float y = xs2[1][0][l15] + xs2[1][1][l15];
  const float d = y - x;  // b2 cancels in the pair difference
  const float sx = 1.f / (1.f + __expf(d));
  const float sy = 1.f - sx;
  float* orow = out + (size_t)myrow * DIM + (l16 << 3);
  if (rok) {
#pragma unroll
    for (int j = 0; j < 4; ++j) {
      const int c = (w << 2) + j;  // wave w covers chunks w*4..w*4+4
      const short8 a0 = Az[(0 * NCHUNK + c) * 64 + l];
      const short8 a1 = Az[(1 * NCHUNK + c) * 64 + l];
      f32x4 o0, o1;
      wcombine(sx, a0, sy, a1, o0, o1);
      *(f32x4*)(orow + (c << 5)) = o0;
      *(f32x4*)(orow + (c << 5) + 4) = o1;
    }
  }
#undef BLOAD
#undef BWRITE
}

extern "C" void kernel_launch(void* const* d_in, const int* in_sizes, int n_in,
                              void* d_out, int out_size, void* d_ws,
                              size_t ws_size, hipStream_t stream) {
  const float* z1 = (const float*)d_in[0];
  const float* z2 = (const float*)d_in[1];
  const float* W1 = (const float*)d_in[2];
  const float* b1 = (const float*)d_in[3];
  const float* W2 = (const float*)d_in[4];
  const float* b2 = (const float*)d_in[5];
  float* out = (float*)d_out;
  const int n = in_sizes[0] / DIM;
  unsigned short* w1s = (unsigned short*)d_ws;  // 512*256*2 = 256 KB

  hipLaunchKernelGGL(w1_swz_kernel, dim3((DIM * HID + 255) / 256), dim3(256),
                     0, stream, W1, w1s);
  const int nwg = (n + ROWS_PB - 1) / ROWS_PB;
  hipLaunchKernelGGL(fa_main_kernel, dim3(nwg), dim3(256), 0, stream, z1, z2,
                     w1s, b1, W2, b2, out, n);
}